// Round 2
// baseline (311.273 us; speedup 1.0000x reference)
//
#include <hip/hip_runtime.h>
#include <cstdint>
#include <cstddef>

// ---------------------------------------------------------------------------
// SelfAttention block on MI355X (gfx950), bf16 MFMA path, round 1.
//   QKV fused GEMM -> barrier-free flash attention -> proj GEMM -> LN.
// ---------------------------------------------------------------------------

typedef short  b16x8 __attribute__((ext_vector_type(8)));   // 8 bf16 (4 VGPRs)
typedef float  f32x4 __attribute__((ext_vector_type(4)));   // MFMA acc

#define AS1 __attribute__((address_space(1)))
#define AS3 __attribute__((address_space(3)))

__device__ __forceinline__ unsigned short f2bf(float f) {   // RNE f32->bf16
    unsigned int u = __builtin_bit_cast(unsigned int, f);
    u += 0x7FFFu + ((u >> 16) & 1u);
    return (unsigned short)(u >> 16);
}

__device__ __forceinline__ unsigned int cvt_pk_bf16(float lo, float hi) {
    unsigned int r;
    asm("v_cvt_pk_bf16_f32 %0, %1, %2" : "=v"(r) : "v"(lo), "v"(hi));
    return r;   // [15:0]=bf16(lo), [31:16]=bf16(hi)
}

// ---------------- convert x (f32) -> bf16 ----------------
__global__ __launch_bounds__(256) void k_cvt_x(const float* __restrict__ x,
                                               unsigned short* __restrict__ xb) {
    int i = blockIdx.x * 256 + threadIdx.x;
    float4 v = ((const float4*)x)[i];
    ushort4 o;
    o.x = f2bf(v.x); o.y = f2bf(v.y); o.z = f2bf(v.z); o.w = f2bf(v.w);
    ((ushort4*)xb)[i] = o;
}

// ---------------- transpose+convert W[k][n] f32 -> Wt[n][k] bf16 ----------------
__global__ __launch_bounds__(1024) void k_cvt_w(
    const float* __restrict__ W0, const float* __restrict__ W1,
    const float* __restrict__ W2, const float* __restrict__ W3,
    unsigned short* __restrict__ T0, unsigned short* __restrict__ T1,
    unsigned short* __restrict__ T2, unsigned short* __restrict__ T3) {
    const float* W = blockIdx.z == 0 ? W0 : blockIdx.z == 1 ? W1 : blockIdx.z == 2 ? W2 : W3;
    unsigned short* T = blockIdx.z == 0 ? T0 : blockIdx.z == 1 ? T1 : blockIdx.z == 2 ? T2 : T3;
    __shared__ float tile[32][33];
    int k0 = blockIdx.x * 32, n0 = blockIdx.y * 32;
    int tx = threadIdx.x, ty = threadIdx.y;
    tile[ty][tx] = W[(size_t)(k0 + ty) * 1024 + n0 + tx];
    __syncthreads();
    T[(size_t)(n0 + ty) * 1024 + k0 + tx] = f2bf(tile[tx][ty]);
}

// ---------------- fused QKV GEMM: C[4096, 3072] ----------------
// A[4096,1024] bf16, Bt[3072][1024] bf16 (Wq|Wk|Wv transposed stacked).
// Scatter to Qb/Kb/Vb [B,H,S,64] bf16; Q scaled by 0.125.
__global__ __launch_bounds__(256) void k_gemm_qkv(
    const unsigned short* __restrict__ A, const unsigned short* __restrict__ Bt,
    const float* __restrict__ bq, const float* __restrict__ bk, const float* __restrict__ bv,
    unsigned short* __restrict__ Qb, unsigned short* __restrict__ Kb,
    unsigned short* __restrict__ Vb) {
    __shared__ unsigned short As[128 * 32];
    __shared__ unsigned short Bs[128 * 32];
    const int tid = threadIdx.x, lane = tid & 63, wid = tid >> 6;
    const int m0 = blockIdx.y * 128, n0 = blockIdx.x * 128;
    const int wr = wid >> 1, wc = wid & 1;
    f32x4 acc[4][4] = {};

    const int srow = wid * 32 + (lane >> 2);
    const int scol = (lane & 3) * 8;
    const unsigned short* Ag = A  + (size_t)(m0 + srow) * 1024 + scol;
    const unsigned short* Bg = Bt + (size_t)(n0 + srow) * 1024 + scol;
    char* AsB = (char*)As + wid * 2048;
    char* BsB = (char*)Bs + wid * 2048;

    for (int kt = 0; kt < 32; ++kt) {
        const unsigned short* a0 = Ag + kt * 32;
        const unsigned short* b0 = Bg + kt * 32;
        __builtin_amdgcn_global_load_lds((const AS1 void*)(a0),             (AS3 void*)(AsB),        16, 0, 0);
        __builtin_amdgcn_global_load_lds((const AS1 void*)(a0 + 16 * 1024), (AS3 void*)(AsB + 1024), 16, 0, 0);
        __builtin_amdgcn_global_load_lds((const AS1 void*)(b0),             (AS3 void*)(BsB),        16, 0, 0);
        __builtin_amdgcn_global_load_lds((const AS1 void*)(b0 + 16 * 1024), (AS3 void*)(BsB + 1024), 16, 0, 0);
        __syncthreads();
        const int g = lane >> 4, r = lane & 15;
        b16x8 af[4], bfr[4];
        for (int mi = 0; mi < 4; ++mi)
            af[mi] = __builtin_bit_cast(b16x8, *(const uint4*)(As + (wr * 64 + mi * 16 + r) * 32 + g * 8));
        for (int ni = 0; ni < 4; ++ni)
            bfr[ni] = __builtin_bit_cast(b16x8, *(const uint4*)(Bs + (wc * 64 + ni * 16 + r) * 32 + g * 8));
        for (int mi = 0; mi < 4; ++mi)
            for (int ni = 0; ni < 4; ++ni)
                acc[mi][ni] = __builtin_amdgcn_mfma_f32_16x16x32_bf16(af[mi], bfr[ni], acc[mi][ni], 0, 0, 0);
        __syncthreads();
    }

    const int g = lane >> 4, r = lane & 15;
    for (int ni = 0; ni < 4; ++ni) {
        int col = n0 + wc * 64 + ni * 16 + r;           // [0, 3072)
        int which = col >> 10, c = col & 1023;
        const float* bp = which == 0 ? bq : which == 1 ? bk : bv;
        unsigned short* dstb = which == 0 ? Qb : which == 1 ? Kb : Vb;
        float bvv = bp[c];
        float sc = which == 0 ? 0.125f : 1.0f;
        int h = c >> 6, hd = c & 63;
        for (int mi = 0; mi < 4; ++mi)
            for (int j = 0; j < 4; ++j) {
                int row = m0 + wr * 64 + mi * 16 + g * 4 + j;
                float v = (acc[mi][ni][j] + bvv) * sc;
                int b = row >> 11, s = row & 2047;
                dstb[((size_t)(b * 16 + h) * 2048 + s) * 64 + hd] = f2bf(v);
            }
    }
}

// ---------------- proj GEMM: BM=128, BN=64 -> grid (16,32)=512 blocks ----------------
__global__ __launch_bounds__(256) void k_gemm_proj(
    const unsigned short* __restrict__ A, const unsigned short* __restrict__ Bt,
    const float* __restrict__ bias, float* __restrict__ out) {
    __shared__ unsigned short As[128 * 32];
    __shared__ unsigned short Bs[64 * 32];
    const int tid = threadIdx.x, lane = tid & 63, wid = tid >> 6;
    const int m0 = blockIdx.y * 128, n0 = blockIdx.x * 64;
    f32x4 acc[2][4] = {};

    const int srow = wid * 32 + (lane >> 2);
    const int scol = (lane & 3) * 8;
    const unsigned short* Ag = A  + (size_t)(m0 + srow) * 1024 + scol;
    const unsigned short* Bg = Bt + (size_t)(n0 + wid * 16 + (lane >> 2)) * 1024 + scol;
    char* AsB = (char*)As + wid * 2048;
    char* BsB = (char*)Bs + wid * 1024;

    for (int kt = 0; kt < 32; ++kt) {
        const unsigned short* a0 = Ag + kt * 32;
        __builtin_amdgcn_global_load_lds((const AS1 void*)(a0),             (AS3 void*)(AsB),        16, 0, 0);
        __builtin_amdgcn_global_load_lds((const AS1 void*)(a0 + 16 * 1024), (AS3 void*)(AsB + 1024), 16, 0, 0);
        __builtin_amdgcn_global_load_lds((const AS1 void*)(Bg + kt * 32),   (AS3 void*)(BsB),        16, 0, 0);
        __syncthreads();
        const int g = lane >> 4, r = lane & 15;
        b16x8 af[2], bfr[4];
        for (int mi = 0; mi < 2; ++mi)
            af[mi] = __builtin_bit_cast(b16x8, *(const uint4*)(As + (wid * 32 + mi * 16 + r) * 32 + g * 8));
        for (int ni = 0; ni < 4; ++ni)
            bfr[ni] = __builtin_bit_cast(b16x8, *(const uint4*)(Bs + (ni * 16 + r) * 32 + g * 8));
        for (int mi = 0; mi < 2; ++mi)
            for (int ni = 0; ni < 4; ++ni)
                acc[mi][ni] = __builtin_amdgcn_mfma_f32_16x16x32_bf16(af[mi], bfr[ni], acc[mi][ni], 0, 0, 0);
        __syncthreads();
    }

    const int g = lane >> 4, r = lane & 15;
    for (int mi = 0; mi < 2; ++mi)
        for (int ni = 0; ni < 4; ++ni) {
            int col = n0 + ni * 16 + r;
            float bv = bias[col];
            for (int j = 0; j < 4; ++j) {
                int row = m0 + wid * 32 + mi * 16 + g * 4 + j;
                out[(size_t)row * 1024 + col] = acc[mi][ni][j] + bv;
            }
        }
}

// ---------------- V [B,H,S,HD] -> Vt [B,H,HD,S] ----------------
__global__ __launch_bounds__(256) void k_transpose_v(const unsigned short* __restrict__ Vb,
                                                     unsigned short* __restrict__ Vt) {
    __shared__ unsigned short T[64][80];
    int bh = blockIdx.y, s0 = blockIdx.x * 64;
    int t = threadIdx.x;
    int r = t >> 2, cq = t & 3;
    const unsigned short* src = Vb + ((size_t)bh * 2048 + s0 + r) * 64 + cq * 16;
    *(uint4*)&T[r][cq * 16]     = *(const uint4*)src;
    *(uint4*)&T[r][cq * 16 + 8] = *(const uint4*)(src + 8);
    __syncthreads();
    __align__(16) unsigned short tmp[16];
    for (int i = 0; i < 16; ++i) tmp[i] = T[cq * 16 + i][r];
    unsigned short* dst = Vt + ((size_t)bh * 64 + r) * 2048 + s0 + cq * 16;
    *(uint4*)dst       = *(uint4*)tmp;
    *(uint4*)(dst + 8) = *(uint4*)(tmp + 8);
}

// ---------------- barrier-free flash attention ----------------
// Qb/Kb: [BH, S, 64] bf16 (Q pre-scaled).  Vt: [BH, 64, S] bf16.
// ctx: [B, S, 1024] bf16.  grid 32x32 (XCD-swizzled), 256 thr = 4 indep waves.
// Per wave: 16 q rows.  Swapped QK^T: S[k][q], lane q = lane&15.
__global__ __launch_bounds__(256) void k_attn(const unsigned short* __restrict__ Qb,
                                              const unsigned short* __restrict__ Kb,
                                              const unsigned short* __restrict__ Vt,
                                              unsigned short* __restrict__ ctx) {
    __shared__ unsigned short Ps[4][16 * 72];   // per-wave P tile, 72-stride (bank-uniform)
    const int tid = threadIdx.x, lane = tid & 63, w = tid >> 6;
    const int r = lane & 15, g = lane >> 4;

    // XCD swizzle: each XCD owns 4 heads (2 MB K/V -> L2-resident)
    int bid = blockIdx.y * gridDim.x + blockIdx.x;
    int xcd = bid & 7, idx = bid >> 3;
    int bh = xcd * 4 + (idx & 3);
    int q0 = (idx >> 2) * 64;
    const int b = bh >> 4, h = bh & 15;

    // hoist Q fragments (B-operand for swapped QK^T)
    const unsigned short* qrow = Qb + ((size_t)bh * 2048 + q0 + w * 16 + r) * 64;
    const b16x8 qf0 = __builtin_bit_cast(b16x8, *(const uint4*)(qrow + g * 8));
    const b16x8 qf1 = __builtin_bit_cast(b16x8, *(const uint4*)(qrow + 32 + g * 8));

    const unsigned short* Kbase = Kb + (size_t)bh * (2048 * 64);
    const unsigned short* Vbase = Vt + (size_t)bh * (64 * 2048);
    unsigned short* Psw = Ps[w];

    float m_run = -1e30f, l_run = 0.f;
    f32x4 oacc[4] = {};

    for (int kt = 0; kt < 32; ++kt) {
        const int k0 = kt * 64;
        // QK^T swapped: sacc[nt] = S[k = k0+nt*16+g*4+j][q = r]
        f32x4 sacc[4];
#pragma unroll
        for (int nt = 0; nt < 4; ++nt) {
            const unsigned short* krow = Kbase + (size_t)(k0 + nt * 16 + r) * 64 + g * 8;
            b16x8 kf0 = __builtin_bit_cast(b16x8, *(const uint4*)(krow));
            b16x8 kf1 = __builtin_bit_cast(b16x8, *(const uint4*)(krow + 32));
            f32x4 z = {};
            z = __builtin_amdgcn_mfma_f32_16x16x32_bf16(kf0, qf0, z, 0, 0, 0);
            z = __builtin_amdgcn_mfma_f32_16x16x32_bf16(kf1, qf1, z, 0, 0, 0);
            sacc[nt] = z;
        }
        // prefetch V fragments; latency hides under softmax VALU
        b16x8 vf[4][2];
#pragma unroll
        for (int nt = 0; nt < 4; ++nt) {
            const unsigned short* vrow = Vbase + (size_t)(nt * 16 + r) * 2048 + k0 + g * 8;
            vf[nt][0] = __builtin_bit_cast(b16x8, *(const uint4*)(vrow));
            vf[nt][1] = __builtin_bit_cast(b16x8, *(const uint4*)(vrow + 32));
        }
        // online softmax: lane owns q=r; row spread over lanes r, r+16, r+32, r+48
        float mx = fmaxf(fmaxf(fmaxf(sacc[0][0], sacc[0][1]), fmaxf(sacc[0][2], sacc[0][3])),
                         fmaxf(fmaxf(sacc[1][0], sacc[1][1]), fmaxf(sacc[1][2], sacc[1][3])));
        mx = fmaxf(mx, fmaxf(fmaxf(fmaxf(sacc[2][0], sacc[2][1]), fmaxf(sacc[2][2], sacc[2][3])),
                             fmaxf(fmaxf(sacc[3][0], sacc[3][1]), fmaxf(sacc[3][2], sacc[3][3]))));
        mx = fmaxf(mx, __shfl_xor(mx, 16, 64));
        mx = fmaxf(mx, __shfl_xor(mx, 32, 64));
        float mn = fmaxf(m_run, mx);
        float al = __expf(m_run - mn);
        m_run = mn;
        float s = 0.f;
#pragma unroll
        for (int nt = 0; nt < 4; ++nt) {
            float p0 = __expf(sacc[nt][0] - mn);
            float p1 = __expf(sacc[nt][1] - mn);
            float p2 = __expf(sacc[nt][2] - mn);
            float p3 = __expf(sacc[nt][3] - mn);
            s += (p0 + p1) + (p2 + p3);
            uint2 d;
            d.x = cvt_pk_bf16(p0, p1);
            d.y = cvt_pk_bf16(p2, p3);
            // P[q=r][k quad nt*16+g*4]: ds_write_b64, wave-local (no barrier)
            *(uint2*)(Psw + r * 72 + nt * 16 + g * 4) = d;
        }
        s += __shfl_xor(s, 16, 64);
        s += __shfl_xor(s, 32, 64);
        l_run = l_run * al + s;
        // rescale O by alpha of row q = g*4+j
#pragma unroll
        for (int j = 0; j < 4; ++j) {
            float aj = __shfl(al, g * 4 + j, 64);
            oacc[0][j] *= aj; oacc[1][j] *= aj; oacc[2][j] *= aj; oacc[3][j] *= aj;
        }
        // PV: A-frag from Ps (own wave's region), B-frag = prefetched V
#pragma unroll
        for (int kk = 0; kk < 2; ++kk) {
            b16x8 pa = __builtin_bit_cast(b16x8, *(const uint4*)(Psw + r * 72 + kk * 32 + g * 8));
#pragma unroll
            for (int nt = 0; nt < 4; ++nt)
                oacc[nt] = __builtin_amdgcn_mfma_f32_16x16x32_bf16(pa, vf[nt][kk], oacc[nt], 0, 0, 0);
        }
    }
    float inv = 1.f / l_run;
#pragma unroll
    for (int j = 0; j < 4; ++j) {
        float ij = __shfl(inv, g * 4 + j, 64);
        unsigned short* dst = ctx + ((size_t)(b * 2048 + q0 + w * 16 + g * 4 + j)) * 1024 + h * 64;
#pragma unroll
        for (int nt = 0; nt < 4; ++nt)
            dst[nt * 16 + r] = f2bf(oacc[nt][j] * ij);
    }
}

// ---------------- residual + LayerNorm ----------------
__global__ __launch_bounds__(256) void k_ln(const float* __restrict__ proj,
                                            const float* __restrict__ x,
                                            const float* __restrict__ gamma,
                                            const float* __restrict__ beta,
                                            float* __restrict__ out) {
    int row = blockIdx.x, t = threadIdx.x;
    int lane = t & 63, w = t >> 6;
    size_t base = (size_t)row * 256;
    float4 p  = ((const float4*)proj)[base + t];
    float4 xv = ((const float4*)x)[base + t];
    float4 y;
    y.x = p.x + xv.x; y.y = p.y + xv.y; y.z = p.z + xv.z; y.w = p.w + xv.w;
    float s  = y.x + y.y + y.z + y.w;
    float ss = y.x * y.x + y.y * y.y + y.z * y.z + y.w * y.w;
    for (int o = 32; o > 0; o >>= 1) { s += __shfl_down(s, o, 64); ss += __shfl_down(ss, o, 64); }
    __shared__ float red[8];
    if (lane == 0) { red[w] = s; red[4 + w] = ss; }
    __syncthreads();
    if (t == 0) {
        red[0] = red[0] + red[1] + red[2] + red[3];
        red[4] = red[4] + red[5] + red[6] + red[7];
    }
    __syncthreads();
    float mu  = red[0] * (1.f / 1024.f);
    float var = red[4] * (1.f / 1024.f) - mu * mu;
    float inv = rsqrtf(var + 1e-5f);
    float4 g  = ((const float4*)gamma)[t];
    float4 be = ((const float4*)beta)[t];
    float4 o4;
    o4.x = (y.x - mu) * inv * g.x + be.x;
    o4.y = (y.y - mu) * inv * g.y + be.y;
    o4.z = (y.z - mu) * inv * g.z + be.z;
    o4.w = (y.w - mu) * inv * g.w + be.w;
    ((float4*)out)[base + t] = o4;
}

// ---------------------------------------------------------------------------
extern "C" void kernel_launch(void* const* d_in, const int* in_sizes, int n_in,
                              void* d_out, int out_size, void* d_ws, size_t ws_size,
                              hipStream_t stream) {
    const float* x  = (const float*)d_in[0];
    const float* Wq = (const float*)d_in[1];
    const float* bq = (const float*)d_in[2];
    const float* Wk = (const float*)d_in[3];
    const float* bk = (const float*)d_in[4];
    const float* Wv = (const float*)d_in[5];
    const float* bv = (const float*)d_in[6];
    const float* Wo = (const float*)d_in[7];
    const float* bo = (const float*)d_in[8];
    const float* gamma = (const float*)d_in[9];
    const float* beta  = (const float*)d_in[10];

    char* ws = (char*)d_ws;
    const size_t MB = 1u << 20;
    unsigned short* xbf   = (unsigned short*)(ws);            // 8 MiB; reused as ctx
    unsigned short* Wqkvt = (unsigned short*)(ws + 8 * MB);   // 6 MiB [3072][1024]
    unsigned short* Wot   = (unsigned short*)(ws + 14 * MB);  // 2 MiB
    unsigned short* Qb    = (unsigned short*)(ws + 16 * MB);  // 8 MiB
    unsigned short* Kb    = (unsigned short*)(ws + 24 * MB);  // 8 MiB
    unsigned short* Vb    = (unsigned short*)(ws + 32 * MB);  // 8 MiB
    unsigned short* Vtg   = (unsigned short*)(ws + 40 * MB);  // 8 MiB
    float* proj = (float*)(ws + 16 * MB);                     // 16 MiB, overlays Qb+Kb
    unsigned short* ctx = xbf;

    k_cvt_x<<<4096, 256, 0, stream>>>(x, xbf);
    k_cvt_w<<<dim3(32, 32, 4), dim3(32, 32), 0, stream>>>(
        Wq, Wk, Wv, Wo, Wqkvt, Wqkvt + 1024 * 1024, Wqkvt + 2 * 1024 * 1024, Wot);
    k_gemm_qkv<<<dim3(24, 32), 256, 0, stream>>>(xbf, Wqkvt, bq, bk, bv, Qb, Kb, Vb);
    k_transpose_v<<<dim3(32, 32), 256, 0, stream>>>(Vb, Vtg);
    k_attn<<<dim3(32, 32), 256, 0, stream>>>(Qb, Kb, Vtg, ctx);
    k_gemm_proj<<<dim3(16, 32), 256, 0, stream>>>(ctx, Wot, bo, proj);
    k_ln<<<4096, 256, 0, stream>>>(proj, x, gamma, beta, (float*)d_out);
}

// Round 3
// 186.124 us; speedup vs baseline: 1.6724x; 1.6724x over previous
//
#include <hip/hip_runtime.h>
#include <cstdint>
#include <cstddef>

// ---------------------------------------------------------------------------
// SelfAttention block on MI355X (gfx950), bf16 MFMA path, round 2.
//   Fused QKV GEMM (scatters Q plain, K/V^T pre-swizzled 64x64 tiles)
//   -> LDS-staged dbuf flash attention (1 barrier/tile, in-reg softmax)
//   -> proj GEMM -> residual LN.
// ---------------------------------------------------------------------------

typedef short  b16x8 __attribute__((ext_vector_type(8)));   // 8 bf16 (4 VGPRs)
typedef float  f32x4 __attribute__((ext_vector_type(4)));   // MFMA acc

#define AS1 __attribute__((address_space(1)))
#define AS3 __attribute__((address_space(3)))

__device__ __forceinline__ unsigned short f2bf(float f) {   // RNE f32->bf16
    unsigned int u = __builtin_bit_cast(unsigned int, f);
    u += 0x7FFFu + ((u >> 16) & 1u);
    return (unsigned short)(u >> 16);
}

__device__ __forceinline__ unsigned int cvt_pk_bf16(float lo, float hi) {
    unsigned int r;
    asm("v_cvt_pk_bf16_f32 %0, %1, %2" : "=v"(r) : "v"(lo), "v"(hi));
    return r;
}

// ---------------- convert x (f32) -> bf16 ----------------
__global__ __launch_bounds__(256) void k_cvt_x(const float* __restrict__ x,
                                               unsigned short* __restrict__ xb) {
    int i = blockIdx.x * 256 + threadIdx.x;
    float4 v = ((const float4*)x)[i];
    ushort4 o;
    o.x = f2bf(v.x); o.y = f2bf(v.y); o.z = f2bf(v.z); o.w = f2bf(v.w);
    ((ushort4*)xb)[i] = o;
}

// ---------------- transpose+convert W[k][n] f32 -> Wt[n][k] bf16 ----------------
__global__ __launch_bounds__(1024) void k_cvt_w(
    const float* __restrict__ W0, const float* __restrict__ W1,
    const float* __restrict__ W2, const float* __restrict__ W3,
    unsigned short* __restrict__ T0, unsigned short* __restrict__ T1,
    unsigned short* __restrict__ T2, unsigned short* __restrict__ T3) {
    const float* W = blockIdx.z == 0 ? W0 : blockIdx.z == 1 ? W1 : blockIdx.z == 2 ? W2 : W3;
    unsigned short* T = blockIdx.z == 0 ? T0 : blockIdx.z == 1 ? T1 : blockIdx.z == 2 ? T2 : T3;
    __shared__ float tile[32][33];
    int k0 = blockIdx.x * 32, n0 = blockIdx.y * 32;
    int tx = threadIdx.x, ty = threadIdx.y;
    tile[ty][tx] = W[(size_t)(k0 + ty) * 1024 + n0 + tx];
    __syncthreads();
    T[(size_t)(n0 + ty) * 1024 + k0 + tx] = f2bf(tile[tx][ty]);
}

// ---------------- fused QKV GEMM: C[4096, 3072] ----------------
// Scatter: Q plain [bh][s][64] (scaled 0.125); K as [bh][kt][64x64 swz tile]
// (row=s&63,col=hd); V^T as [bh][kt][64x64 swz tile] (row=hd,col=s&63).
__global__ __launch_bounds__(256) void k_gemm_qkv(
    const unsigned short* __restrict__ A, const unsigned short* __restrict__ Bt,
    const float* __restrict__ bq, const float* __restrict__ bk, const float* __restrict__ bv,
    unsigned short* __restrict__ Qb, unsigned short* __restrict__ Kt,
    unsigned short* __restrict__ Vt) {
    __shared__ unsigned short As[128 * 32];
    __shared__ unsigned short Bs[128 * 32];
    const int tid = threadIdx.x, lane = tid & 63, wid = tid >> 6;
    const int m0 = blockIdx.y * 128, n0 = blockIdx.x * 128;
    const int wr = wid >> 1, wc = wid & 1;
    f32x4 acc[4][4] = {};

    const int srow = wid * 32 + (lane >> 2);
    const int scol = (lane & 3) * 8;
    const unsigned short* Ag = A  + (size_t)(m0 + srow) * 1024 + scol;
    const unsigned short* Bg = Bt + (size_t)(n0 + srow) * 1024 + scol;
    char* AsB = (char*)As + wid * 2048;
    char* BsB = (char*)Bs + wid * 2048;

    for (int kt = 0; kt < 32; ++kt) {
        const unsigned short* a0 = Ag + kt * 32;
        const unsigned short* b0 = Bg + kt * 32;
        __builtin_amdgcn_global_load_lds((const AS1 void*)(a0),             (AS3 void*)(AsB),        16, 0, 0);
        __builtin_amdgcn_global_load_lds((const AS1 void*)(a0 + 16 * 1024), (AS3 void*)(AsB + 1024), 16, 0, 0);
        __builtin_amdgcn_global_load_lds((const AS1 void*)(b0),             (AS3 void*)(BsB),        16, 0, 0);
        __builtin_amdgcn_global_load_lds((const AS1 void*)(b0 + 16 * 1024), (AS3 void*)(BsB + 1024), 16, 0, 0);
        __syncthreads();
        const int g = lane >> 4, r = lane & 15;
        b16x8 af[4], bfr[4];
        for (int mi = 0; mi < 4; ++mi)
            af[mi] = __builtin_bit_cast(b16x8, *(const uint4*)(As + (wr * 64 + mi * 16 + r) * 32 + g * 8));
        for (int ni = 0; ni < 4; ++ni)
            bfr[ni] = __builtin_bit_cast(b16x8, *(const uint4*)(Bs + (wc * 64 + ni * 16 + r) * 32 + g * 8));
        for (int mi = 0; mi < 4; ++mi)
            for (int ni = 0; ni < 4; ++ni)
                acc[mi][ni] = __builtin_amdgcn_mfma_f32_16x16x32_bf16(af[mi], bfr[ni], acc[mi][ni], 0, 0, 0);
        __syncthreads();
    }

    const int g = lane >> 4, r = lane & 15;
    for (int ni = 0; ni < 4; ++ni) {
        int col = n0 + wc * 64 + ni * 16 + r;           // [0, 3072)
        int which = col >> 10, c = col & 1023;
        const float* bp = which == 0 ? bq : which == 1 ? bk : bv;
        float bvv = bp[c];
        int h = c >> 6, hd = c & 63;
        for (int mi = 0; mi < 4; ++mi)
            for (int j = 0; j < 4; ++j) {
                int row = m0 + wr * 64 + mi * 16 + g * 4 + j;
                float v = acc[mi][ni][j] + bvv;
                int b = row >> 11, s = row & 2047;
                size_t bh = (size_t)(b * 16 + h);
                if (which == 0) {
                    Qb[(bh * 2048 + s) * 64 + hd] = f2bf(v * 0.125f);
                } else if (which == 1) {
                    int tt = s >> 6, kr = s & 63;
                    Kt[(bh * 32 + tt) * 4096 + ((kr * 64 + hd) ^ ((kr & 7) << 3))] = f2bf(v);
                } else {
                    int tt = s >> 6, cc = s & 63;
                    Vt[(bh * 32 + tt) * 4096 + ((hd * 64 + cc) ^ ((hd & 7) << 3))] = f2bf(v);
                }
            }
    }
}

// ---------------- proj GEMM: BM=128, BN=64 -> grid (16,32)=512 blocks ----------------
__global__ __launch_bounds__(256) void k_gemm_proj(
    const unsigned short* __restrict__ A, const unsigned short* __restrict__ Bt,
    const float* __restrict__ bias, float* __restrict__ out) {
    __shared__ unsigned short As[128 * 32];
    __shared__ unsigned short Bs[64 * 32];
    const int tid = threadIdx.x, lane = tid & 63, wid = tid >> 6;
    const int m0 = blockIdx.y * 128, n0 = blockIdx.x * 64;
    f32x4 acc[2][4] = {};

    const int srow = wid * 32 + (lane >> 2);
    const int scol = (lane & 3) * 8;
    const unsigned short* Ag = A  + (size_t)(m0 + srow) * 1024 + scol;
    const unsigned short* Bg = Bt + (size_t)(n0 + wid * 16 + (lane >> 2)) * 1024 + scol;
    char* AsB = (char*)As + wid * 2048;
    char* BsB = (char*)Bs + wid * 1024;

    for (int kt = 0; kt < 32; ++kt) {
        const unsigned short* a0 = Ag + kt * 32;
        __builtin_amdgcn_global_load_lds((const AS1 void*)(a0),             (AS3 void*)(AsB),        16, 0, 0);
        __builtin_amdgcn_global_load_lds((const AS1 void*)(a0 + 16 * 1024), (AS3 void*)(AsB + 1024), 16, 0, 0);
        __builtin_amdgcn_global_load_lds((const AS1 void*)(Bg + kt * 32),   (AS3 void*)(BsB),        16, 0, 0);
        __syncthreads();
        const int g = lane >> 4, r = lane & 15;
        b16x8 af[2], bfr[4];
        for (int mi = 0; mi < 2; ++mi)
            af[mi] = __builtin_bit_cast(b16x8, *(const uint4*)(As + (wid * 32 + mi * 16 + r) * 32 + g * 8));
        for (int ni = 0; ni < 4; ++ni)
            bfr[ni] = __builtin_bit_cast(b16x8, *(const uint4*)(Bs + (ni * 16 + r) * 32 + g * 8));
        for (int mi = 0; mi < 2; ++mi)
            for (int ni = 0; ni < 4; ++ni)
                acc[mi][ni] = __builtin_amdgcn_mfma_f32_16x16x32_bf16(af[mi], bfr[ni], acc[mi][ni], 0, 0, 0);
        __syncthreads();
    }

    const int g = lane >> 4, r = lane & 15;
    for (int mi = 0; mi < 2; ++mi)
        for (int ni = 0; ni < 4; ++ni) {
            int col = n0 + ni * 16 + r;
            float bv = bias[col];
            for (int j = 0; j < 4; ++j) {
                int row = m0 + wid * 32 + mi * 16 + g * 4 + j;
                out[(size_t)row * 1024 + col] = acc[mi][ni][j] + bv;
            }
        }
}

// ---------------- flash attention: LDS dbuf, 1 barrier/tile ----------------
// Qb: [bh][s][64] bf16 (pre-scaled).  Kt/Vt: [bh][32][64x64 swz tile] bf16.
// ctx: [B,S,1024] bf16.  grid 1024 (XCD-swizzled), 4 waves; wave w: 16 q rows.
#define TSWZ(row, byteoff) ((((row) * 128) + (byteoff)) ^ (((row) & 7) << 4))

__global__ __launch_bounds__(256) void k_attn(const unsigned short* __restrict__ Qb,
                                              const unsigned short* __restrict__ Kt,
                                              const unsigned short* __restrict__ Vt,
                                              unsigned short* __restrict__ ctx) {
    __shared__ unsigned short Ks[2][4096];
    __shared__ unsigned short Vs[2][4096];
    __shared__ unsigned short Ps[4][1024];
    const int tid = threadIdx.x, lane = tid & 63, w = tid >> 6;
    const int r = lane & 15, g = lane >> 4;

    int bid = blockIdx.x;
    int xcd = bid & 7, idx = bid >> 3;
    int bh = xcd * 4 + (idx & 3);      // 4 heads per XCD -> K/V L2-resident
    int q0 = (idx >> 2) * 64;
    const int b = bh >> 4, h = bh & 15;

    // hoist Q fragments (B-operand of swapped QK^T)
    const unsigned short* qrow = Qb + ((size_t)bh * 2048 + q0 + w * 16 + r) * 64;
    const b16x8 qf0 = __builtin_bit_cast(b16x8, *(const uint4*)(qrow + g * 8));
    const b16x8 qf1 = __builtin_bit_cast(b16x8, *(const uint4*)(qrow + 32 + g * 8));

    const unsigned short* Kg = Kt + (size_t)bh * 32 * 4096;
    const unsigned short* Vg = Vt + (size_t)bh * 32 * 4096;
    char* Psw = (char*)Ps[w];

#define STAGE(kt, buf) do {                                                              \
        const unsigned short* _ks = Kg + (size_t)(kt) * 4096 + w * 512 + lane * 8;       \
        const unsigned short* _vs = Vg + (size_t)(kt) * 4096 + w * 512 + lane * 8;       \
        char* _kd = (char*)Ks[buf] + w * 1024;                                           \
        char* _vd = (char*)Vs[buf] + w * 1024;                                           \
        __builtin_amdgcn_global_load_lds((const AS1 void*)_ks,          (AS3 void*)_kd,          16, 0, 0); \
        __builtin_amdgcn_global_load_lds((const AS1 void*)(_ks + 2048), (AS3 void*)(_kd + 4096), 16, 0, 0); \
        __builtin_amdgcn_global_load_lds((const AS1 void*)_vs,          (AS3 void*)_vd,          16, 0, 0); \
        __builtin_amdgcn_global_load_lds((const AS1 void*)(_vs + 2048), (AS3 void*)(_vd + 4096), 16, 0, 0); \
    } while (0)

    STAGE(0, 0);
    float m_run = -1e30f, l_run = 0.f;
    f32x4 oacc[4] = {};
    __syncthreads();

    for (int kt = 0; kt < 32; ++kt) {
        const int cur = kt & 1;
        // K fragments (A-operand rows = k)
        b16x8 kf[4][2];
#pragma unroll
        for (int nt = 0; nt < 4; ++nt) {
            int row = nt * 16 + r;
            kf[nt][0] = __builtin_bit_cast(b16x8, *(const uint4*)((char*)Ks[cur] + TSWZ(row, g * 16)));
            kf[nt][1] = __builtin_bit_cast(b16x8, *(const uint4*)((char*)Ks[cur] + TSWZ(row, 64 + g * 16)));
        }
        if (kt < 31) STAGE(kt + 1, cur ^ 1);      // async prefetch, drained by barrier
        // QK^T swapped: lane (r,g) gets S[k=nt*16+g*4+j][q=r]
        f32x4 sacc[4];
#pragma unroll
        for (int nt = 0; nt < 4; ++nt) {
            f32x4 z = {};
            z = __builtin_amdgcn_mfma_f32_16x16x32_bf16(kf[nt][0], qf0, z, 0, 0, 0);
            z = __builtin_amdgcn_mfma_f32_16x16x32_bf16(kf[nt][1], qf1, z, 0, 0, 0);
            sacc[nt] = z;
        }
        // V fragments (B-operand rows = hd) — latency hides under softmax
        b16x8 vf[4][2];
#pragma unroll
        for (int nt = 0; nt < 4; ++nt) {
            int row = nt * 16 + r;
            vf[nt][0] = __builtin_bit_cast(b16x8, *(const uint4*)((char*)Vs[cur] + TSWZ(row, g * 16)));
            vf[nt][1] = __builtin_bit_cast(b16x8, *(const uint4*)((char*)Vs[cur] + TSWZ(row, 64 + g * 16)));
        }
        // online softmax, lane owns q=r (replicated over g)
        float mx = fmaxf(fmaxf(fmaxf(sacc[0][0], sacc[0][1]), fmaxf(sacc[0][2], sacc[0][3])),
                         fmaxf(fmaxf(sacc[1][0], sacc[1][1]), fmaxf(sacc[1][2], sacc[1][3])));
        mx = fmaxf(mx, fmaxf(fmaxf(fmaxf(sacc[2][0], sacc[2][1]), fmaxf(sacc[2][2], sacc[2][3])),
                             fmaxf(fmaxf(sacc[3][0], sacc[3][1]), fmaxf(sacc[3][2], sacc[3][3]))));
        mx = fmaxf(mx, __shfl_xor(mx, 16, 64));
        mx = fmaxf(mx, __shfl_xor(mx, 32, 64));
        float mn = fmaxf(m_run, mx);
        float al = __expf(m_run - mn);
        m_run = mn;
        float s = 0.f;
#pragma unroll
        for (int nt = 0; nt < 4; ++nt) {
            float p0 = __expf(sacc[nt][0] - mn);
            float p1 = __expf(sacc[nt][1] - mn);
            float p2 = __expf(sacc[nt][2] - mn);
            float p3 = __expf(sacc[nt][3] - mn);
            s += (p0 + p1) + (p2 + p3);
            uint2 d;
            d.x = cvt_pk_bf16(p0, p1);
            d.y = cvt_pk_bf16(p2, p3);
            *(uint2*)(Psw + TSWZ(r, nt * 32 + g * 8)) = d;   // wave-local, no barrier
        }
        s += __shfl_xor(s, 16, 64);
        s += __shfl_xor(s, 32, 64);
        l_run = l_run * al + s;
#pragma unroll
        for (int j = 0; j < 4; ++j) {            // rescale O rows q=g*4+j
            float aj = __shfl(al, g * 4 + j, 64);
            oacc[0][j] *= aj; oacc[1][j] *= aj; oacc[2][j] *= aj; oacc[3][j] *= aj;
        }
        // PV: A = P[q=r][k], B = V^T[hd]
#pragma unroll
        for (int kk = 0; kk < 2; ++kk) {
            b16x8 pa = __builtin_bit_cast(b16x8, *(const uint4*)(Psw + TSWZ(r, kk * 64 + g * 16)));
#pragma unroll
            for (int nt = 0; nt < 4; ++nt)
                oacc[nt] = __builtin_amdgcn_mfma_f32_16x16x32_bf16(pa, vf[nt][kk], oacc[nt], 0, 0, 0);
        }
        __syncthreads();        // staged buf^1 complete; all waves done with cur
    }
    float inv = 1.f / l_run;
#pragma unroll
    for (int j = 0; j < 4; ++j) {
        float ij = __shfl(inv, g * 4 + j, 64);
        unsigned short* dst = ctx + ((size_t)(b * 2048 + q0 + w * 16 + g * 4 + j)) * 1024 + h * 64;
#pragma unroll
        for (int nt = 0; nt < 4; ++nt)
            dst[nt * 16 + r] = f2bf(oacc[nt][j] * ij);
    }
#undef STAGE
}

// ---------------- residual + LayerNorm ----------------
__global__ __launch_bounds__(256) void k_ln(const float* __restrict__ proj,
                                            const float* __restrict__ x,
                                            const float* __restrict__ gamma,
                                            const float* __restrict__ beta,
                                            float* __restrict__ out) {
    int row = blockIdx.x, t = threadIdx.x;
    int lane = t & 63, w = t >> 6;
    size_t base = (size_t)row * 256;
    float4 p  = ((const float4*)proj)[base + t];
    float4 xv = ((const float4*)x)[base + t];
    float4 y;
    y.x = p.x + xv.x; y.y = p.y + xv.y; y.z = p.z + xv.z; y.w = p.w + xv.w;
    float s  = y.x + y.y + y.z + y.w;
    float ss = y.x * y.x + y.y * y.y + y.z * y.z + y.w * y.w;
    for (int o = 32; o > 0; o >>= 1) { s += __shfl_down(s, o, 64); ss += __shfl_down(ss, o, 64); }
    __shared__ float red[8];
    if (lane == 0) { red[w] = s; red[4 + w] = ss; }
    __syncthreads();
    if (t == 0) {
        red[0] = red[0] + red[1] + red[2] + red[3];
        red[4] = red[4] + red[5] + red[6] + red[7];
    }
    __syncthreads();
    float mu  = red[0] * (1.f / 1024.f);
    float var = red[4] * (1.f / 1024.f) - mu * mu;
    float inv = rsqrtf(var + 1e-5f);
    float4 gg = ((const float4*)gamma)[t];
    float4 be = ((const float4*)beta)[t];
    float4 o4;
    o4.x = (y.x - mu) * inv * gg.x + be.x;
    o4.y = (y.y - mu) * inv * gg.y + be.y;
    o4.z = (y.z - mu) * inv * gg.z + be.z;
    o4.w = (y.w - mu) * inv * gg.w + be.w;
    ((float4*)out)[base + t] = o4;
}

// ---------------------------------------------------------------------------
extern "C" void kernel_launch(void* const* d_in, const int* in_sizes, int n_in,
                              void* d_out, int out_size, void* d_ws, size_t ws_size,
                              hipStream_t stream) {
    const float* x  = (const float*)d_in[0];
    const float* Wq = (const float*)d_in[1];
    const float* bq = (const float*)d_in[2];
    const float* Wk = (const float*)d_in[3];
    const float* bk = (const float*)d_in[4];
    const float* Wv = (const float*)d_in[5];
    const float* bv = (const float*)d_in[6];
    const float* Wo = (const float*)d_in[7];
    const float* bo = (const float*)d_in[8];
    const float* gamma = (const float*)d_in[9];
    const float* beta  = (const float*)d_in[10];

    char* ws = (char*)d_ws;
    const size_t MB = 1u << 20;
    unsigned short* xbf   = (unsigned short*)(ws);            // 8 MiB; reused as ctx
    unsigned short* Wqkvt = (unsigned short*)(ws + 8 * MB);   // 6 MiB [3072][1024]
    unsigned short* Wot   = (unsigned short*)(ws + 14 * MB);  // 2 MiB
    unsigned short* Qb    = (unsigned short*)(ws + 16 * MB);  // 8 MiB
    unsigned short* Kt    = (unsigned short*)(ws + 24 * MB);  // 8 MiB (swz tiles)
    unsigned short* Vt    = (unsigned short*)(ws + 32 * MB);  // 8 MiB (swz tiles)
    float* proj = (float*)(ws + 16 * MB);                     // 16 MiB, overlays Qb+Kt
    unsigned short* ctx = xbf;

    k_cvt_x<<<4096, 256, 0, stream>>>(x, xbf);
    k_cvt_w<<<dim3(32, 32, 4), dim3(32, 32), 0, stream>>>(
        Wq, Wk, Wv, Wo, Wqkvt, Wqkvt + 1024 * 1024, Wqkvt + 2 * 1024 * 1024, Wot);
    k_gemm_qkv<<<dim3(24, 32), 256, 0, stream>>>(xbf, Wqkvt, bq, bk, bv, Qb, Kt, Vt);
    k_attn<<<1024, 256, 0, stream>>>(Qb, Kt, Vt, ctx);
    k_gemm_proj<<<dim3(16, 32), 256, 0, stream>>>(ctx, Wot, bo, proj);
    k_ln<<<4096, 256, 0, stream>>>(proj, x, gamma, beta, (float*)d_out);
}

// Round 4
// 165.989 us; speedup vs baseline: 1.8753x; 1.1213x over previous
//
#include <hip/hip_runtime.h>
#include <cstdint>
#include <cstddef>

// ---------------------------------------------------------------------------
// SelfAttention block on MI355X (gfx950), bf16 MFMA path, round 3.
//   Fused QKV GEMM (K/V^T pre-swizzled 64x64 tiles, Q scaled 0.125*log2e)
//   -> flash attention: 2 waves x 2 q-chains, shared K/V frags, exp2 softmax,
//      defer-max, lane-local l partials -> proj GEMM -> residual LN.
// ---------------------------------------------------------------------------

typedef short  b16x8 __attribute__((ext_vector_type(8)));   // 8 bf16 (4 VGPRs)
typedef float  f32x4 __attribute__((ext_vector_type(4)));   // MFMA acc

#define AS1 __attribute__((address_space(1)))
#define AS3 __attribute__((address_space(3)))

__device__ __forceinline__ unsigned short f2bf(float f) {   // RNE f32->bf16
    unsigned int u = __builtin_bit_cast(unsigned int, f);
    u += 0x7FFFu + ((u >> 16) & 1u);
    return (unsigned short)(u >> 16);
}

__device__ __forceinline__ unsigned int cvt_pk_bf16(float lo, float hi) {
    unsigned int r;
    asm("v_cvt_pk_bf16_f32 %0, %1, %2" : "=v"(r) : "v"(lo), "v"(hi));
    return r;
}

__device__ __forceinline__ float exp2_fast(float x) {       // 2^x, raw v_exp
    float r;
    asm("v_exp_f32 %0, %1" : "=v"(r) : "v"(x));
    return r;
}

// ---------------- convert x (f32) -> bf16 ----------------
__global__ __launch_bounds__(256) void k_cvt_x(const float* __restrict__ x,
                                               unsigned short* __restrict__ xb) {
    int i = blockIdx.x * 256 + threadIdx.x;
    float4 v = ((const float4*)x)[i];
    ushort4 o;
    o.x = f2bf(v.x); o.y = f2bf(v.y); o.z = f2bf(v.z); o.w = f2bf(v.w);
    ((ushort4*)xb)[i] = o;
}

// ---------------- transpose+convert W[k][n] f32 -> Wt[n][k] bf16 ----------------
__global__ __launch_bounds__(1024) void k_cvt_w(
    const float* __restrict__ W0, const float* __restrict__ W1,
    const float* __restrict__ W2, const float* __restrict__ W3,
    unsigned short* __restrict__ T0, unsigned short* __restrict__ T1,
    unsigned short* __restrict__ T2, unsigned short* __restrict__ T3) {
    const float* W = blockIdx.z == 0 ? W0 : blockIdx.z == 1 ? W1 : blockIdx.z == 2 ? W2 : W3;
    unsigned short* T = blockIdx.z == 0 ? T0 : blockIdx.z == 1 ? T1 : blockIdx.z == 2 ? T2 : T3;
    __shared__ float tile[32][33];
    int k0 = blockIdx.x * 32, n0 = blockIdx.y * 32;
    int tx = threadIdx.x, ty = threadIdx.y;
    tile[ty][tx] = W[(size_t)(k0 + ty) * 1024 + n0 + tx];
    __syncthreads();
    T[(size_t)(n0 + ty) * 1024 + k0 + tx] = f2bf(tile[tx][ty]);
}

// ---------------- fused QKV GEMM: C[4096, 3072] ----------------
// Scatter: Q plain [bh][s][64] scaled 0.125*log2(e); K as [bh][kt][64x64 swz]
// (row=s&63,col=hd); V^T as [bh][kt][64x64 swz] (row=hd,col=s&63).
__global__ __launch_bounds__(256) void k_gemm_qkv(
    const unsigned short* __restrict__ A, const unsigned short* __restrict__ Bt,
    const float* __restrict__ bq, const float* __restrict__ bk, const float* __restrict__ bv,
    unsigned short* __restrict__ Qb, unsigned short* __restrict__ Kt,
    unsigned short* __restrict__ Vt) {
    __shared__ unsigned short As[128 * 32];
    __shared__ unsigned short Bs[128 * 32];
    const int tid = threadIdx.x, lane = tid & 63, wid = tid >> 6;
    const int m0 = blockIdx.y * 128, n0 = blockIdx.x * 128;
    const int wr = wid >> 1, wc = wid & 1;
    f32x4 acc[4][4] = {};

    const int srow = wid * 32 + (lane >> 2);
    const int scol = (lane & 3) * 8;
    const unsigned short* Ag = A  + (size_t)(m0 + srow) * 1024 + scol;
    const unsigned short* Bg = Bt + (size_t)(n0 + srow) * 1024 + scol;
    char* AsB = (char*)As + wid * 2048;
    char* BsB = (char*)Bs + wid * 2048;

    for (int kt = 0; kt < 32; ++kt) {
        const unsigned short* a0 = Ag + kt * 32;
        const unsigned short* b0 = Bg + kt * 32;
        __builtin_amdgcn_global_load_lds((const AS1 void*)(a0),             (AS3 void*)(AsB),        16, 0, 0);
        __builtin_amdgcn_global_load_lds((const AS1 void*)(a0 + 16 * 1024), (AS3 void*)(AsB + 1024), 16, 0, 0);
        __builtin_amdgcn_global_load_lds((const AS1 void*)(b0),             (AS3 void*)(BsB),        16, 0, 0);
        __builtin_amdgcn_global_load_lds((const AS1 void*)(b0 + 16 * 1024), (AS3 void*)(BsB + 1024), 16, 0, 0);
        __syncthreads();
        const int g = lane >> 4, r = lane & 15;
        b16x8 af[4], bfr[4];
        for (int mi = 0; mi < 4; ++mi)
            af[mi] = __builtin_bit_cast(b16x8, *(const uint4*)(As + (wr * 64 + mi * 16 + r) * 32 + g * 8));
        for (int ni = 0; ni < 4; ++ni)
            bfr[ni] = __builtin_bit_cast(b16x8, *(const uint4*)(Bs + (wc * 64 + ni * 16 + r) * 32 + g * 8));
        for (int mi = 0; mi < 4; ++mi)
            for (int ni = 0; ni < 4; ++ni)
                acc[mi][ni] = __builtin_amdgcn_mfma_f32_16x16x32_bf16(af[mi], bfr[ni], acc[mi][ni], 0, 0, 0);
        __syncthreads();
    }

    const int g = lane >> 4, r = lane & 15;
    for (int ni = 0; ni < 4; ++ni) {
        int col = n0 + wc * 64 + ni * 16 + r;           // [0, 3072)
        int which = col >> 10, c = col & 1023;
        const float* bp = which == 0 ? bq : which == 1 ? bk : bv;
        float bvv = bp[c];
        int h = c >> 6, hd = c & 63;
        for (int mi = 0; mi < 4; ++mi)
            for (int j = 0; j < 4; ++j) {
                int row = m0 + wr * 64 + mi * 16 + g * 4 + j;
                float v = acc[mi][ni][j] + bvv;
                int b = row >> 11, s = row & 2047;
                size_t bh = (size_t)(b * 16 + h);
                if (which == 0) {
                    // fold 1/sqrt(64) * log2(e): scores land in log2 domain
                    Qb[(bh * 2048 + s) * 64 + hd] = f2bf(v * 0.180336881f);
                } else if (which == 1) {
                    int tt = s >> 6, kr = s & 63;
                    Kt[(bh * 32 + tt) * 4096 + ((kr * 64 + hd) ^ ((kr & 7) << 3))] = f2bf(v);
                } else {
                    int tt = s >> 6, cc = s & 63;
                    Vt[(bh * 32 + tt) * 4096 + ((hd * 64 + cc) ^ ((hd & 7) << 3))] = f2bf(v);
                }
            }
    }
}

// ---------------- proj GEMM: BM=128, BN=64 -> grid (16,32)=512 blocks ----------------
__global__ __launch_bounds__(256) void k_gemm_proj(
    const unsigned short* __restrict__ A, const unsigned short* __restrict__ Bt,
    const float* __restrict__ bias, float* __restrict__ out) {
    __shared__ unsigned short As[128 * 32];
    __shared__ unsigned short Bs[64 * 32];
    const int tid = threadIdx.x, lane = tid & 63, wid = tid >> 6;
    const int m0 = blockIdx.y * 128, n0 = blockIdx.x * 64;
    f32x4 acc[2][4] = {};

    const int srow = wid * 32 + (lane >> 2);
    const int scol = (lane & 3) * 8;
    const unsigned short* Ag = A  + (size_t)(m0 + srow) * 1024 + scol;
    const unsigned short* Bg = Bt + (size_t)(n0 + wid * 16 + (lane >> 2)) * 1024 + scol;
    char* AsB = (char*)As + wid * 2048;
    char* BsB = (char*)Bs + wid * 1024;

    for (int kt = 0; kt < 32; ++kt) {
        const unsigned short* a0 = Ag + kt * 32;
        __builtin_amdgcn_global_load_lds((const AS1 void*)(a0),             (AS3 void*)(AsB),        16, 0, 0);
        __builtin_amdgcn_global_load_lds((const AS1 void*)(a0 + 16 * 1024), (AS3 void*)(AsB + 1024), 16, 0, 0);
        __builtin_amdgcn_global_load_lds((const AS1 void*)(Bg + kt * 32),   (AS3 void*)(BsB),        16, 0, 0);
        __syncthreads();
        const int g = lane >> 4, r = lane & 15;
        b16x8 af[2], bfr[4];
        for (int mi = 0; mi < 2; ++mi)
            af[mi] = __builtin_bit_cast(b16x8, *(const uint4*)(As + (wid * 32 + mi * 16 + r) * 32 + g * 8));
        for (int ni = 0; ni < 4; ++ni)
            bfr[ni] = __builtin_bit_cast(b16x8, *(const uint4*)(Bs + (ni * 16 + r) * 32 + g * 8));
        for (int mi = 0; mi < 2; ++mi)
            for (int ni = 0; ni < 4; ++ni)
                acc[mi][ni] = __builtin_amdgcn_mfma_f32_16x16x32_bf16(af[mi], bfr[ni], acc[mi][ni], 0, 0, 0);
        __syncthreads();
    }

    const int g = lane >> 4, r = lane & 15;
    for (int mi = 0; mi < 2; ++mi)
        for (int ni = 0; ni < 4; ++ni) {
            int col = n0 + ni * 16 + r;
            float bv = bias[col];
            for (int j = 0; j < 4; ++j) {
                int row = m0 + wid * 32 + mi * 16 + g * 4 + j;
                out[(size_t)row * 1024 + col] = acc[mi][ni][j] + bv;
            }
        }
}

// ---------------- flash attention: 2 waves x 2 chains, LDS dbuf ----------------
// Qb: [bh][s][64] bf16 (pre-scaled, log2 domain).  Kt/Vt: [bh][32][64x64 swz].
// ctx: [B,S,1024] bf16.  grid 1024, 128 thr (2 waves); wave w: chains c=0,1,
// chain handles q rows q0 + (w*2+c)*16 .. +16.  K/V frags shared by chains.
#define TSWZ(row, byteoff) ((((row) * 128) + (byteoff)) ^ (((row) & 7) << 4))

__global__ __launch_bounds__(128, 2) void k_attn(const unsigned short* __restrict__ Qb,
                                                 const unsigned short* __restrict__ Kt,
                                                 const unsigned short* __restrict__ Vt,
                                                 unsigned short* __restrict__ ctx) {
    __shared__ unsigned short Ks[2][4096];
    __shared__ unsigned short Vs[2][4096];
    __shared__ unsigned short Ps[4][1024];      // [w*2+c], 16 rows x 64 k, swz
    const int tid = threadIdx.x, lane = tid & 63, w = tid >> 6;   // w in {0,1}
    const int r = lane & 15, g = lane >> 4;

    int bid = blockIdx.x;
    int xcd = bid & 7, idx = bid >> 3;
    int bh = xcd * 4 + (idx & 3);               // 4 heads/XCD -> K/V L2-resident
    int q0 = (idx >> 2) * 64;
    const int b = bh >> 4, h = bh & 15;

    // hoist Q fragments (B-operand of swapped QK^T), both chains
    b16x8 qf[2][2];
#pragma unroll
    for (int c = 0; c < 2; ++c) {
        const unsigned short* qrow = Qb + ((size_t)bh * 2048 + q0 + (w * 2 + c) * 16 + r) * 64;
        qf[c][0] = __builtin_bit_cast(b16x8, *(const uint4*)(qrow + g * 8));
        qf[c][1] = __builtin_bit_cast(b16x8, *(const uint4*)(qrow + 32 + g * 8));
    }

    const unsigned short* Kg = Kt + (size_t)bh * 32 * 4096;
    const unsigned short* Vg = Vt + (size_t)bh * 32 * 4096;

#define STAGE(kt, buf) do {                                                         \
        const unsigned short* _kt = Kg + (size_t)(kt) * 4096;                       \
        const unsigned short* _vt = Vg + (size_t)(kt) * 4096;                       \
        _Pragma("unroll")                                                           \
        for (int _i = 0; _i < 4; ++_i) {                                            \
            __builtin_amdgcn_global_load_lds((const AS1 void*)(_kt + _i * 1024 + w * 512 + lane * 8), \
                                             (AS3 void*)((char*)Ks[buf] + _i * 2048 + w * 1024), 16, 0, 0); \
            __builtin_amdgcn_global_load_lds((const AS1 void*)(_vt + _i * 1024 + w * 512 + lane * 8), \
                                             (AS3 void*)((char*)Vs[buf] + _i * 2048 + w * 1024), 16, 0, 0); \
        }                                                                           \
    } while (0)

    float m_run[2] = {-1e30f, -1e30f};
    float lpart[2] = {0.f, 0.f};                // lane-local partial denominator
    f32x4 oacc[2][4] = {};

    STAGE(0, 0);
    __syncthreads();

    for (int kt = 0; kt < 32; ++kt) {
        const int cur = kt & 1;
        // K fragments (A-operand rows = k), shared by both chains
        b16x8 kf[4][2];
#pragma unroll
        for (int nt = 0; nt < 4; ++nt) {
            int row = nt * 16 + r;
            kf[nt][0] = __builtin_bit_cast(b16x8, *(const uint4*)((char*)Ks[cur] + TSWZ(row, g * 16)));
            kf[nt][1] = __builtin_bit_cast(b16x8, *(const uint4*)((char*)Ks[cur] + TSWZ(row, 64 + g * 16)));
        }
        if (kt < 31) STAGE(kt + 1, cur ^ 1);     // async prefetch, drained at barrier
        // QK^T swapped: lane (r,g) gets S[k=nt*16+g*4+j][q=r], log2 domain
        f32x4 sacc[2][4];
#pragma unroll
        for (int c = 0; c < 2; ++c)
#pragma unroll
            for (int nt = 0; nt < 4; ++nt) {
                f32x4 z = {};
                z = __builtin_amdgcn_mfma_f32_16x16x32_bf16(kf[nt][0], qf[c][0], z, 0, 0, 0);
                z = __builtin_amdgcn_mfma_f32_16x16x32_bf16(kf[nt][1], qf[c][1], z, 0, 0, 0);
                sacc[c][nt] = z;
            }
        // V fragments (B-operand rows = hd), shared by both chains
        b16x8 vf[4][2];
#pragma unroll
        for (int nt = 0; nt < 4; ++nt) {
            int row = nt * 16 + r;
            vf[nt][0] = __builtin_bit_cast(b16x8, *(const uint4*)((char*)Vs[cur] + TSWZ(row, g * 16)));
            vf[nt][1] = __builtin_bit_cast(b16x8, *(const uint4*)((char*)Vs[cur] + TSWZ(row, 64 + g * 16)));
        }
        // online softmax per chain (exp2 domain, defer-max THR=8)
#pragma unroll
        for (int c = 0; c < 2; ++c) {
            float mx = fmaxf(
                fmaxf(fmaxf(fmaxf(sacc[c][0][0], sacc[c][0][1]), fmaxf(sacc[c][0][2], sacc[c][0][3])),
                      fmaxf(fmaxf(sacc[c][1][0], sacc[c][1][1]), fmaxf(sacc[c][1][2], sacc[c][1][3]))),
                fmaxf(fmaxf(fmaxf(sacc[c][2][0], sacc[c][2][1]), fmaxf(sacc[c][2][2], sacc[c][2][3])),
                      fmaxf(fmaxf(sacc[c][3][0], sacc[c][3][1]), fmaxf(sacc[c][3][2], sacc[c][3][3]))));
            mx = fmaxf(mx, __shfl_xor(mx, 16, 64));
            mx = fmaxf(mx, __shfl_xor(mx, 32, 64));
            if (!__all(mx <= m_run[c] + 8.f)) {          // rescale path (rare)
                float mn = fmaxf(m_run[c], mx);
                float al = exp2_fast(m_run[c] - mn);
                m_run[c] = mn;
                lpart[c] *= al;
#pragma unroll
                for (int j = 0; j < 4; ++j) {
                    float aj = __shfl(al, g * 4 + j, 64);
                    oacc[c][0][j] *= aj; oacc[c][1][j] *= aj;
                    oacc[c][2][j] *= aj; oacc[c][3][j] *= aj;
                }
            }
            char* Psw = (char*)Ps[w * 2 + c];
            float mc = m_run[c];
#pragma unroll
            for (int nt = 0; nt < 4; ++nt) {
                float p0 = exp2_fast(sacc[c][nt][0] - mc);
                float p1 = exp2_fast(sacc[c][nt][1] - mc);
                float p2 = exp2_fast(sacc[c][nt][2] - mc);
                float p3 = exp2_fast(sacc[c][nt][3] - mc);
                lpart[c] += (p0 + p1) + (p2 + p3);
                uint2 d;
                d.x = cvt_pk_bf16(p0, p1);
                d.y = cvt_pk_bf16(p2, p3);
                *(uint2*)(Psw + TSWZ(r, nt * 32 + g * 8)) = d;   // wave-local
            }
        }
        // PV per chain: A = P[q=r][k], B = shared V^T frags
#pragma unroll
        for (int c = 0; c < 2; ++c) {
            char* Psw = (char*)Ps[w * 2 + c];
#pragma unroll
            for (int kk = 0; kk < 2; ++kk) {
                b16x8 pa = __builtin_bit_cast(b16x8, *(const uint4*)(Psw + TSWZ(r, kk * 64 + g * 16)));
#pragma unroll
                for (int nt = 0; nt < 4; ++nt)
                    oacc[c][nt] = __builtin_amdgcn_mfma_f32_16x16x32_bf16(pa, vf[nt][kk], oacc[c][nt], 0, 0, 0);
            }
        }
        __syncthreads();        // staged buf^1 complete; all waves done with cur
    }
#pragma unroll
    for (int c = 0; c < 2; ++c) {
        float l = lpart[c];
        l += __shfl_xor(l, 16, 64);
        l += __shfl_xor(l, 32, 64);
        float inv = 1.f / l;
#pragma unroll
        for (int j = 0; j < 4; ++j) {
            float ij = __shfl(inv, g * 4 + j, 64);
            unsigned short* dst = ctx + ((size_t)(b * 2048 + q0 + (w * 2 + c) * 16 + g * 4 + j)) * 1024 + h * 64;
#pragma unroll
            for (int nt = 0; nt < 4; ++nt)
                dst[nt * 16 + r] = f2bf(oacc[c][nt][j] * ij);
        }
    }
#undef STAGE
}

// ---------------- residual + LayerNorm ----------------
__global__ __launch_bounds__(256) void k_ln(const float* __restrict__ proj,
                                            const float* __restrict__ x,
                                            const float* __restrict__ gamma,
                                            const float* __restrict__ beta,
                                            float* __restrict__ out) {
    int row = blockIdx.x, t = threadIdx.x;
    int lane = t & 63, w = t >> 6;
    size_t base = (size_t)row * 256;
    float4 p  = ((const float4*)proj)[base + t];
    float4 xv = ((const float4*)x)[base + t];
    float4 y;
    y.x = p.x + xv.x; y.y = p.y + xv.y; y.z = p.z + xv.z; y.w = p.w + xv.w;
    float s  = y.x + y.y + y.z + y.w;
    float ss = y.x * y.x + y.y * y.y + y.z * y.z + y.w * y.w;
    for (int o = 32; o > 0; o >>= 1) { s += __shfl_down(s, o, 64); ss += __shfl_down(ss, o, 64); }
    __shared__ float red[8];
    if (lane == 0) { red[w] = s; red[4 + w] = ss; }
    __syncthreads();
    if (t == 0) {
        red[0] = red[0] + red[1] + red[2] + red[3];
        red[4] = red[4] + red[5] + red[6] + red[7];
    }
    __syncthreads();
    float mu  = red[0] * (1.f / 1024.f);
    float var = red[4] * (1.f / 1024.f) - mu * mu;
    float inv = rsqrtf(var + 1e-5f);
    float4 gg = ((const float4*)gamma)[t];
    float4 be = ((const float4*)beta)[t];
    float4 o4;
    o4.x = (y.x - mu) * inv * gg.x + be.x;
    o4.y = (y.y - mu) * inv * gg.y + be.y;
    o4.z = (y.z - mu) * inv * gg.z + be.z;
    o4.w = (y.w - mu) * inv * gg.w + be.w;
    ((float4*)out)[base + t] = o4;
}

// ---------------------------------------------------------------------------
extern "C" void kernel_launch(void* const* d_in, const int* in_sizes, int n_in,
                              void* d_out, int out_size, void* d_ws, size_t ws_size,
                              hipStream_t stream) {
    const float* x  = (const float*)d_in[0];
    const float* Wq = (const float*)d_in[1];
    const float* bq = (const float*)d_in[2];
    const float* Wk = (const float*)d_in[3];
    const float* bk = (const float*)d_in[4];
    const float* Wv = (const float*)d_in[5];
    const float* bv = (const float*)d_in[6];
    const float* Wo = (const float*)d_in[7];
    const float* bo = (const float*)d_in[8];
    const float* gamma = (const float*)d_in[9];
    const float* beta  = (const float*)d_in[10];

    char* ws = (char*)d_ws;
    const size_t MB = 1u << 20;
    unsigned short* xbf   = (unsigned short*)(ws);            // 8 MiB; reused as ctx
    unsigned short* Wqkvt = (unsigned short*)(ws + 8 * MB);   // 6 MiB [3072][1024]
    unsigned short* Wot   = (unsigned short*)(ws + 14 * MB);  // 2 MiB
    unsigned short* Qb    = (unsigned short*)(ws + 16 * MB);  // 8 MiB
    unsigned short* Kt    = (unsigned short*)(ws + 24 * MB);  // 8 MiB (swz tiles)
    unsigned short* Vt    = (unsigned short*)(ws + 32 * MB);  // 8 MiB (swz tiles)
    float* proj = (float*)(ws + 16 * MB);                     // 16 MiB, overlays Qb+Kt
    unsigned short* ctx = xbf;

    k_cvt_x<<<4096, 256, 0, stream>>>(x, xbf);
    k_cvt_w<<<dim3(32, 32, 4), dim3(32, 32), 0, stream>>>(
        Wq, Wk, Wv, Wo, Wqkvt, Wqkvt + 1024 * 1024, Wqkvt + 2 * 1024 * 1024, Wot);
    k_gemm_qkv<<<dim3(24, 32), 256, 0, stream>>>(xbf, Wqkvt, bq, bk, bv, Qb, Kt, Vt);
    k_attn<<<1024, 128, 0, stream>>>(Qb, Kt, Vt, ctx);
    k_gemm_proj<<<dim3(16, 32), 256, 0, stream>>>(ctx, Wot, bo, proj);
    k_ln<<<4096, 256, 0, stream>>>(proj, x, gamma, beta, (float*)d_out);
}